// Round 7
// baseline (112.889 us; speedup 1.0000x reference)
//
#include <hip/hip_runtime.h>
#include <hip/hip_bf16.h>

// ---------- types ----------
typedef short s8v  __attribute__((ext_vector_type(8)));   // 8 x bf16 (4 VGPRs)
typedef float f16v __attribute__((ext_vector_type(16)));  // 32x32 accumulator

#define NUM_EMBEDS 8192
#define EMBED_DIM  256
#define BATCH      16
#define HW         1024
#define NVEC       (BATCH * HW)              // 16384
#define OUT0_ELEMS (BATCH * EMBED_DIM * HW)  // 4194304
#define NSPLIT     8                         // column splits (1 per XCD)
#define COLS_PER_S 1024                      // 8192 / NSPLIT
#define NTILES     32                        // COLS_PER_S / 32

// k_argmin LDS map (dynamic, 39936 B):
//   buf0 @ 0      B tile [32 cols][560B padded rows]  (17920 B)
//   buf1 @ 17920
//   e2   @ 35840  this block's 1024 e2 floats (4 KiB)
// stride 560 = 35*16, gcd(35,8)=1 -> 16B slot classes are a permutation
// -> conflict-free ds_read_b128 AND ds_write_b128.
#define BSTRIDE 560
#define BUFB  (32 * BSTRIDE)        // 17920
#define E2L   (2 * BUFB)            // 35840
#define SMEM3 (E2L + 4096)          // 39936

// ---------- workspace layout (ends 12.75 MB — below proven-safe 13.2 MB) ----------
#define WS_XB   0              // 8 MB  bf16 x rows
#define WS_EB   8388608        // 4 MB  bf16 codebook
#define WS_E2   12582912       // 32 KB e2
#define WS_AMIN 12615680       // 128 KB packed u64 (scorekey<<32 | col)
#define WS_LOSS 12746752       // 4 B

static __device__ __forceinline__ unsigned short f32_to_bf16_rne(float f) {
    unsigned int u = __float_as_uint(f);
    unsigned int r = u + 0x7FFFu + ((u >> 16) & 1u);
    return (unsigned short)(r >> 16);
}

// order-preserving float -> u32 (total order, min-compatible)
static __device__ __forceinline__ unsigned f32_key(float f) {
    unsigned u = __float_as_uint(f);
    return (u & 0x80000000u) ? ~u : (u | 0x80000000u);
}

static __device__ __forceinline__ void gload_lds16(const void* g, void* l) {
    __builtin_amdgcn_global_load_lds(
        (const __attribute__((address_space(1))) unsigned int*)g,
        (__attribute__((address_space(3))) unsigned int*)l, 16, 0, 0);
}

// ---------- kernel 0: init amin + loss ----------
__global__ void k_init(unsigned long long* __restrict__ amin, float* __restrict__ loss) {
    const int i = blockIdx.x * 256 + threadIdx.x;
    amin[i] = ~0ULL;
    if (i == 0) *loss = 0.0f;
}

// ---------- kernel 1: transpose x [16][256][1024] f32 -> xb [16384][256] bf16 ----------
__global__ void k_transpose_x(const float* __restrict__ x, unsigned short* __restrict__ xb) {
    __shared__ float t[32][33];
    const int tx = threadIdx.x;          // 0..31
    const int ty = threadIdx.y;          // 0..7
    const int hw0 = blockIdx.x * 32;
    const int c0  = blockIdx.y * 32;
    const int b   = blockIdx.z;
    #pragma unroll
    for (int i = 0; i < 4; ++i) {
        const int c = c0 + ty + i * 8;
        t[ty + i * 8][tx] = x[((b * EMBED_DIM + c) << 10) + hw0 + tx];
    }
    __syncthreads();
    #pragma unroll
    for (int i = 0; i < 4; ++i) {
        const int hw = hw0 + ty + i * 8;
        const int n = b * HW + hw;
        xb[n * EMBED_DIM + c0 + tx] = f32_to_bf16_rne(t[tx][ty + i * 8]);
    }
}

// ---------- kernel 2: codebook f32 -> bf16 + e2 ----------
__global__ void k_convert_cb(const float* __restrict__ cb, unsigned short* __restrict__ eb,
                             float* __restrict__ e2) {
    const int e = blockIdx.x;
    const int tid = threadIdx.x;      // 0..255
    const float v = cb[e * EMBED_DIM + tid];
    eb[e * EMBED_DIM + tid] = f32_to_bf16_rne(v);
    float s = v * v;
    #pragma unroll
    for (int off = 32; off > 0; off >>= 1) s += __shfl_down(s, off, 64);
    __shared__ float ls[4];
    const int lane = tid & 63, wid = tid >> 6;
    if (lane == 0) ls[wid] = s;
    __syncthreads();
    if (tid == 0) e2[e] = ls[0] + ls[1] + ls[2] + ls[3];
}

// ---------- kernel 3: fused GEMM + argmin ----------
// Grid 256 = 32 row-blocks x 8 col-splits; s = blk&7 pins one 512KB codebook
// slice per XCD (L2-resident). Block: 512 thr = 8 waves; 64 rows/wave
// (afr[2][16] = 128 VGPR pinned, each B frag feeds 2 MFMAs -> LDS 2-reuse);
// tile = 32 cols, reg-staged into padded-row LDS, issue-early/write-late.
__global__ void __launch_bounds__(512, 2)
k_argmin(const unsigned short* __restrict__ xb, const unsigned short* __restrict__ eb,
         const float* __restrict__ e2, unsigned long long* __restrict__ amin) {
    extern __shared__ char smem[];
    const int tid  = threadIdx.x;
    const int lane = tid & 63;
    const int w    = tid >> 6;           // wave 0..7
    const int l31  = lane & 31;
    const int hi   = lane >> 5;          // 0/1
    const int s    = blockIdx.x & 7;
    const int rb   = blockIdx.x >> 3;
    const int row0 = rb * 512;
    const int cb0  = s * COLS_PER_S;

    const char* xbB = (const char*)xb;
    const char* ebB = (const char*)eb;
    const char* e2B = (const char*)e2;

    // ---- A fragments straight from global: 64 rows/wave ----
    // 32x32x16 A layout: lane row = l31 (+mr*32), k = ks*16 + hi*8 + j
    s8v afr[2][16];
    #pragma unroll
    for (int mr = 0; mr < 2; ++mr) {
        const int arow = row0 + w * 64 + mr * 32 + l31;
        #pragma unroll
        for (int ks = 0; ks < 16; ++ks)
            afr[mr][ks] = *reinterpret_cast<const s8v*>(
                xbB + ((size_t)arow << 9) + ks * 32 + hi * 16);
    }

    // ---- e2 slice (4 KiB): waves 0..3 stage 1 KiB each ----
    if (w < 4)
        gload_lds16(e2B + ((size_t)cb0 << 2) + w * 1024 + lane * 16,
                    smem + E2L + w * 1024);

    // ---- stage tile 0 (reg-staged, padded rows) ----
    // instr p = w*2+j covers rows 2p,2p+1; lane l -> row 2p+hi, chunk l31.
    int4 st0, st1;
    {
        const char* src = ebB + ((size_t)cb0 << 9);
        st0 = *reinterpret_cast<const int4*>(src + (w * 2 + 0) * 1024 + lane * 16);
        st1 = *reinterpret_cast<const int4*>(src + (w * 2 + 1) * 1024 + lane * 16);
        *reinterpret_cast<int4*>(smem + (2 * (w * 2 + 0) + hi) * BSTRIDE + l31 * 16) = st0;
        *reinterpret_cast<int4*>(smem + (2 * (w * 2 + 1) + hi) * BSTRIDE + l31 * 16) = st1;
    }

    // pin A in registers (no sinking/rematerialization)
    #pragma unroll
    for (int mr = 0; mr < 2; ++mr)
        #pragma unroll
        for (int ks = 0; ks < 16; ++ks)
            asm volatile("" : "+v"(afr[mr][ks]));

    __syncthreads();

    float    minv[2][16];
    unsigned mpack[16];                  // lo16: mr0 local col, hi16: mr1 local col
    #pragma unroll
    for (int r = 0; r < 16; ++r) { minv[0][r] = 3.4e38f; minv[1][r] = 3.4e38f; mpack[r] = 0; }

    for (int t = 0; t < NTILES; ++t) {
        const int cur = (t & 1) * BUFB;
        const int nxt = BUFB - cur;

        // issue next-tile loads early (latency hides under MFMA phase)
        if (t < NTILES - 1) {
            const char* src = ebB + ((size_t)(cb0 + (t + 1) * 32) << 9);
            st0 = *reinterpret_cast<const int4*>(src + (w * 2 + 0) * 1024 + lane * 16);
            st1 = *reinterpret_cast<const int4*>(src + (w * 2 + 1) * 1024 + lane * 16);
        }

        const float ev = *reinterpret_cast<const float*>(smem + E2L + t * 128 + l31 * 4);
        const char* bb = smem + cur + l31 * BSTRIDE;

        f16v a0{}, a1{};
        #pragma unroll
        for (int ks = 0; ks < 16; ++ks) {
            const s8v bf = *reinterpret_cast<const s8v*>(bb + (ks * 2 + hi) * 16);
            a0 = __builtin_amdgcn_mfma_f32_32x32x16_bf16(afr[0][ks], bf, a0, 0, 0, 0);
            a1 = __builtin_amdgcn_mfma_f32_32x32x16_bf16(afr[1][ks], bf, a1, 0, 0, 0);
        }

        const unsigned colr = (unsigned)(t * 32 + l31);
        #pragma unroll
        for (int r = 0; r < 16; ++r) {
            const float s0 = fmaf(-2.0f, a0[r], ev);
            if (s0 < minv[0][r]) { minv[0][r] = s0; mpack[r] = (mpack[r] & 0xFFFF0000u) | colr; }
            const float s1 = fmaf(-2.0f, a1[r], ev);
            if (s1 < minv[1][r]) { minv[1][r] = s1; mpack[r] = (mpack[r] & 0x0000FFFFu) | (colr << 16); }
        }

        // write next tile late (loads have landed during MFMA)
        if (t < NTILES - 1) {
            *reinterpret_cast<int4*>(smem + nxt + (2 * (w * 2 + 0) + hi) * BSTRIDE + l31 * 16) = st0;
            *reinterpret_cast<int4*>(smem + nxt + (2 * (w * 2 + 1) + hi) * BSTRIDE + l31 * 16) = st1;
        }
        __syncthreads();
    }

    // ---- reduce over 32 col-lanes (butterfly), then device-scope atomicMin ----
    #pragma unroll
    for (int mr = 0; mr < 2; ++mr)
        #pragma unroll
        for (int r = 0; r < 16; ++r) {
            float v = minv[mr][r];
            int   c = cb0 + (int)((mpack[r] >> (mr * 16)) & 0xFFFFu);
            #pragma unroll
            for (int m = 1; m <= 16; m <<= 1) {
                const float v2 = __shfl_xor(v, m, 64);
                const int   c2 = __shfl_xor(c, m, 64);
                if (v2 < v || (v2 == v && c2 < c)) { v = v2; c = c2; }
            }
            if (l31 == 0) {
                const int row_g = row0 + w * 64 + mr * 32 + (r & 3) + 8 * (r >> 2) + 4 * hi;
                const unsigned long long key =
                    ((unsigned long long)f32_key(v) << 32) | (unsigned)c;
                atomicMin(&amin[row_g], key);
            }
        }
}

// ---------- kernel 4: gather + straight-through output + loss partial ----------
__global__ void __launch_bounds__(256)
k_gather_loss(const float* __restrict__ x, const float* __restrict__ cb,
              const unsigned long long* __restrict__ amin, float* __restrict__ out,
              float* __restrict__ loss) {
    __shared__ float q[32][257];
    __shared__ int e_s[32];
    const int tid = threadIdx.x;
    const int hw0 = (blockIdx.x & 31) * 32;
    const int b   = blockIdx.x >> 5;
    const int n0  = (b << 10) + hw0;
    if (tid < 32) e_s[tid] = (int)(amin[n0 + tid] & 0xFFFFFFFFu);
    __syncthreads();
    #pragma unroll 8
    for (int r = 0; r < 32; ++r)
        q[r][tid] = cb[(size_t)e_s[r] * EMBED_DIM + tid];
    __syncthreads();
    const int tx = tid & 31;    // hw offset within tile
    const int ty = tid >> 5;    // 0..7  (channel group)
    float sum = 0.f;
    #pragma unroll
    for (int i = 0; i < 32; ++i) {
        const int c = ty * 32 + i;
        const float qv = q[tx][c];
        const int o = ((b * EMBED_DIM + c) << 10) + hw0 + tx;
        const float xv = x[o];
        out[o] = qv;
        const float d = qv - xv;
        sum = fmaf(d, d, sum);
    }
    #pragma unroll
    for (int off = 32; off > 0; off >>= 1) sum += __shfl_down(sum, off, 64);
    __shared__ float ls[4];
    const int lane = tid & 63, wid = tid >> 6;
    if (lane == 0) ls[wid] = sum;
    __syncthreads();
    if (tid == 0) atomicAdd(loss, ls[0] + ls[1] + ls[2] + ls[3]);
}

// ---------- kernel 5: finalize loss ----------
__global__ void k_finalize(const float* __restrict__ loss, float* __restrict__ out) {
    out[OUT0_ELEMS] = loss[0] * (1.25f / (float)OUT0_ELEMS);
}

extern "C" void kernel_launch(void* const* d_in, const int* in_sizes, int n_in,
                              void* d_out, int out_size, void* d_ws, size_t ws_size,
                              hipStream_t stream) {
    const float* x  = (const float*)d_in[0];
    const float* cb = (const float*)d_in[1];
    float* out = (float*)d_out;

    char* ws = (char*)d_ws;
    unsigned short* xb = (unsigned short*)(ws + WS_XB);
    unsigned short* eb = (unsigned short*)(ws + WS_EB);
    float* e2 = (float*)(ws + WS_E2);
    unsigned long long* amin = (unsigned long long*)(ws + WS_AMIN);
    float* loss = (float*)(ws + WS_LOSS);

    k_init<<<dim3(NVEC / 256), dim3(256), 0, stream>>>(amin, loss);
    k_transpose_x<<<dim3(32, 8, 16), dim3(32, 8, 1), 0, stream>>>(x, xb);
    k_convert_cb<<<dim3(NUM_EMBEDS), dim3(256), 0, stream>>>(cb, eb, e2);
    k_argmin<<<dim3(32 * NSPLIT), dim3(512), SMEM3, stream>>>(xb, eb, e2, amin);
    k_gather_loss<<<dim3(512), dim3(256), 0, stream>>>(x, cb, amin, out, loss);
    k_finalize<<<dim3(1), dim3(1), 0, stream>>>(loss, out);
}